// Round 1
// baseline (332.449 us; speedup 1.0000x reference)
//
#include <hip/hip_runtime.h>
#include <hip/hip_bf16.h>

typedef __attribute__((ext_vector_type(8))) short short8;
typedef __attribute__((ext_vector_type(4))) float f32x4;
typedef __attribute__((ext_vector_type(2))) float f32x2;

// ---- workspace layout (bytes) ----
#define WS_ZE     0u           // bf16 hi  [B][N][64] : 1 MB
#define WS_ZELO   (1u<<20)     // bf16 lo  [B][N][64] : 1 MB
#define WS_BOOKS  (2u<<20)     // images: k*131072 + h*65536 + part*32768 (part0=hi,part1=lo)
#define WS_BOOKST (4u<<20)     // booksT images: k*65536 + h*32768 (hi only)
#define WS_ZN2    (5u<<20)     // f32 [B][N] 32 KB
#define WS_BS2    ((5u<<20)+32768u) // f32 [K][S] 32 KB

__device__ __forceinline__ unsigned short f2bf(float x) {
  __hip_bfloat16 h = __float2bfloat16(x);
  return __builtin_bit_cast(unsigned short, h);
}
__device__ __forceinline__ float bf2f(unsigned short u) {
  union { unsigned int i; float f; } x; x.i = ((unsigned int)u) << 16; return x.f;
}

// ---------------- prep: ze -> bf16 hi/lo + row norms ----------------
__global__ __launch_bounds__(256) void prep_ze_k(const float* __restrict__ ze,
                                                 char* __restrict__ ws) {
  int t = blockIdx.x * 256 + threadIdx.x;     // one per (b,n), 8192
  if (t >= 8 * 1024) return;
  const float* row = ze + t * 64;
  unsigned short* dh = (unsigned short*)(ws + WS_ZE) + t * 64;
  unsigned short* dl = (unsigned short*)(ws + WS_ZELO) + t * 64;
  float s = 0.f;
#pragma unroll 8
  for (int d = 0; d < 64; ++d) {
    float v = row[d]; s += v * v;
    unsigned short h = f2bf(v);
    dh[d] = h;
    dl[d] = f2bf(v - bf2f(h));
  }
  ((float*)(ws + WS_ZN2))[t] = s;
}

// ---------------- prep: books -> swizzled bf16 images + norms + precision ----------------
__global__ __launch_bounds__(256) void prep_books_k(const float* __restrict__ books,
                                                    const float* __restrict__ lpq,
                                                    char* __restrict__ ws,
                                                    float* __restrict__ d_out) {
  int t = blockIdx.x * 256 + threadIdx.x;     // one per (k,s), 8192
  if (t == 0) d_out[524288] = 0.5f / fmaxf(expf(lpq[0]), 1e-10f);
  if (t >= 16 * 512) return;
  int k = t >> 9, s = t & 511;
  const float* row = books + t * 64;
  __align__(16) unsigned short hi16[64];
  __align__(16) unsigned short lo16[64];
  float sum = 0.f;
#pragma unroll 8
  for (int d = 0; d < 64; ++d) {
    float v = row[d]; sum += v * v;
    unsigned short h = f2bf(v);
    hi16[d] = h;
    lo16[d] = f2bf(v - bf2f(h));
  }
  ((float*)(ws + WS_BS2))[t] = sum;
  const int sl = s & 255;
  const unsigned swz = (unsigned)(s & 7) << 4;
  // s-major images (for matmul1 A-operand), XOR-swizzled rows of 128 B
  char* imgh = ws + WS_BOOKS + k * 131072 + (s >> 8) * 65536 + sl * 128;
  char* imgl = imgh + 32768;
#pragma unroll
  for (int c = 0; c < 8; ++c) {
    *(short8*)(imgh + (((unsigned)(c * 16)) ^ swz)) = *(const short8*)(hi16 + c * 8);
    *(short8*)(imgl + (((unsigned)(c * 16)) ^ swz)) = *(const short8*)(lo16 + c * 8);
  }
  // d-major transposed image (for matmul2 A-operand), rows of 512 B
  char* imgT = ws + WS_BOOKST + k * 65536 + (s >> 8) * 32768;
#pragma unroll
  for (int d = 0; d < 64; ++d)
    *(unsigned short*)(imgT + d * 512 + (((unsigned)(sl * 2)) ^ (((unsigned)(d & 7)) << 4))) = hi16[d];
}

// ---------------- main ----------------
__device__ __forceinline__ void stage32k(char* ldsdst, const char* gsrc, int tid) {
#pragma unroll
  for (int c = 0; c < 4; ++c) {
    const int off = c * 8192 + tid * 16;
    __builtin_amdgcn_global_load_lds(
        (const __attribute__((address_space(1))) unsigned int*)(gsrc + off),
        (__attribute__((address_space(3))) unsigned int*)(ldsdst + off),
        16, 0, 0);
  }
}

__global__ __launch_bounds__(512, 4)
void gvq_main(const float* __restrict__ gum, const float* __restrict__ cprobs,
              const float* __restrict__ lpq, char* __restrict__ ws,
              float* __restrict__ d_out) {
  __shared__ char lds[81920];
  char* booksbuf = lds;            // 32 KB (staged halves, reused)
  char* logitsb  = lds + 32768;    // 32 KB f32 [16][512] swizzled
  char* encb     = lds + 65536;    // 16 KB bf16 [16][512] swizzled

  const int tid  = threadIdx.x;
  const int lane = tid & 63;
  const int wave = tid >> 6;       // 0..7
  const int l15  = lane & 15;
  const int g4   = lane >> 4;      // 0..3

  const int bid   = blockIdx.x;
  const int b     = bid >> 6;
  const int ntile = bid & 63;
  const int n0    = ntile * 16;

  const float prec = 0.5f / fmaxf(expf(lpq[0]), 1e-10f);

  const unsigned short* zh = (const unsigned short*)(ws + WS_ZE)   + (b * 1024 + n0 + l15) * 64;
  const unsigned short* zl = (const unsigned short*)(ws + WS_ZELO) + (b * 1024 + n0 + l15) * 64;
  const short8 zf0h = *(const short8*)(zh + g4 * 8);
  const short8 zf1h = *(const short8*)(zh + 32 + g4 * 8);
  const short8 zf0l = *(const short8*)(zl + g4 * 8);
  const short8 zf1l = *(const short8*)(zl + 32 + g4 * 8);
  const float zn2v = ((const float*)(ws + WS_ZN2))[b * 1024 + n0 + l15];

  f32x4 zacc[4] = {{0,0,0,0},{0,0,0,0},{0,0,0,0},{0,0,0,0}};

#pragma unroll 1
  for (int k = 0; k < 16; ++k) {
    const float cp = cprobs[b * 16 + k];
    const char* bimg  = ws + WS_BOOKS  + k * 131072;
    const char* bTimg = ws + WS_BOOKST + k * 65536;
    const float* bs2k = (const float*)(ws + WS_BS2) + k * 512;

    // ---- matmul1: logitsT[s][n] via 3-term hi/lo bf16 MFMA ----
#pragma unroll 1
    for (int h = 0; h < 2; ++h) {
      __syncthreads();                                  // booksbuf free
      stage32k(booksbuf, bimg + h * 65536, tid);        // books hi half
      __syncthreads();
      f32x4 cc[2] = {{0,0,0,0},{0,0,0,0}};
#pragma unroll
      for (int st = 0; st < 2; ++st) {
        const int srow = (wave * 2 + st) * 16 + l15;    // 0..255
        const unsigned swz = (unsigned)(srow & 7) << 4;
        const char* arow = booksbuf + srow * 128;
        short8 a0 = *(const short8*)(arow + (((unsigned)(g4 * 16)) ^ swz));
        short8 a1 = *(const short8*)(arow + (((unsigned)(64 + g4 * 16)) ^ swz));
        cc[st] = __builtin_amdgcn_mfma_f32_16x16x32_bf16(a0, zf0h, cc[st], 0, 0, 0);
        cc[st] = __builtin_amdgcn_mfma_f32_16x16x32_bf16(a1, zf1h, cc[st], 0, 0, 0);
        cc[st] = __builtin_amdgcn_mfma_f32_16x16x32_bf16(a0, zf0l, cc[st], 0, 0, 0);
        cc[st] = __builtin_amdgcn_mfma_f32_16x16x32_bf16(a1, zf1l, cc[st], 0, 0, 0);
      }
      __syncthreads();                                  // hi reads done
      stage32k(booksbuf, bimg + h * 65536 + 32768, tid);// books lo half
      __syncthreads();
#pragma unroll
      for (int st = 0; st < 2; ++st) {
        const int stl = wave * 2 + st;
        const int srow = stl * 16 + l15;
        const unsigned swz = (unsigned)(srow & 7) << 4;
        const char* arow = booksbuf + srow * 128;
        short8 a0 = *(const short8*)(arow + (((unsigned)(g4 * 16)) ^ swz));
        short8 a1 = *(const short8*)(arow + (((unsigned)(64 + g4 * 16)) ^ swz));
        f32x4 c = cc[st];
        c = __builtin_amdgcn_mfma_f32_16x16x32_bf16(a0, zf0h, c, 0, 0, 0);
        c = __builtin_amdgcn_mfma_f32_16x16x32_bf16(a1, zf1h, c, 0, 0, 0);
        const int stg = h * 16 + stl;                   // global stile 0..31
        const f32x4 bs2v = *(const f32x4*)(bs2k + stg * 16 + g4 * 4);
        f32x4 lg;
        lg.x = (2.f * c.x - zn2v - bs2v.x) * prec;
        lg.y = (2.f * c.y - zn2v - bs2v.y) * prec;
        lg.z = (2.f * c.z - zn2v - bs2v.z) * prec;
        lg.w = (2.f * c.w - zn2v - bs2v.w) * prec;
        const unsigned swzn = (unsigned)(l15 & 7) << 4;
        *(f32x4*)(logitsb + l15 * 2048 + (((unsigned)(stg * 64 + g4 * 16)) ^ swzn)) = lg;
      }
    }
    __syncthreads();                 // logits complete, booksbuf free
    stage32k(booksbuf, bTimg, tid);  // booksT h0 — overlaps phase 2

    // ---- phase 2: gumbel + two softmaxes, wave handles rows 2w, 2w+1 ----
#pragma unroll 1
    for (int r = 0; r < 2; ++r) {
      const int n = wave * 2 + r;
      const unsigned swzn = (unsigned)(n & 7) << 4;
      const char* lrow = logitsb + n * 2048;
      const f32x4 L0 = *(const f32x4*)(lrow + (((unsigned)(lane * 32)) ^ swzn));
      const f32x4 L1 = *(const f32x4*)(lrow + (((unsigned)(lane * 32 + 16)) ^ swzn));
      const float* urow = gum + ((long)((b * 16 + k) * 1024 + n0 + n)) * 512 + lane * 8;
      const f32x4 U0 = *(const f32x4*)(urow);
      const f32x4 U1 = *(const f32x4*)(urow + 4);
      float lv[8] = {L0.x, L0.y, L0.z, L0.w, L1.x, L1.y, L1.z, L1.w};
      float uv[8] = {U0.x, U0.y, U0.z, U0.w, U1.x, U1.y, U1.z, U1.w};
      float av[8];
      float m1 = -1e30f, m2 = -1e30f;
#pragma unroll
      for (int j = 0; j < 8; ++j) {
        float gg = -__logf(-__logf(uv[j] + 1e-10f) + 1e-10f);
        av[j] = (lv[j] + gg) * 2.0f;      // /TEMPERATURE(0.5)
        m1 = fmaxf(m1, lv[j]); m2 = fmaxf(m2, av[j]);
      }
#pragma unroll
      for (int o = 32; o; o >>= 1) {
        m1 = fmaxf(m1, __shfl_xor(m1, o));
        m2 = fmaxf(m2, __shfl_xor(m2, o));
      }
      float e1v[8], e2v[8], z1 = 0.f, z2 = 0.f;
#pragma unroll
      for (int j = 0; j < 8; ++j) {
        e1v[j] = __expf(lv[j] - m1); z1 += e1v[j];
        e2v[j] = __expf(av[j] - m2); z2 += e2v[j];
      }
#pragma unroll
      for (int o = 32; o; o >>= 1) { z1 += __shfl_xor(z1, o); z2 += __shfl_xor(z2, o); }
      const float rz1 = 1.0f / z1;
      const float lz1 = __logf(z1);
      const float esc = cp / z2;            // fold c_probs into enc
      const long obase = ((long)((b * 16 + k) * 1024 + n0 + n)) * 512 + lane * 8;
      float* pp = d_out + 524289 + obase;
      float* pl = pp + 67108864;
#pragma unroll
      for (int j = 0; j < 8; ++j) {
        pp[j] = e1v[j] * rz1;
        pl[j] = (lv[j] - m1) - lz1;
      }
      union { unsigned short u[8]; short8 v; } ew;
#pragma unroll
      for (int j = 0; j < 8; ++j) ew.u[j] = f2bf(e2v[j] * esc);
      *(short8*)(encb + n * 1024 + (((unsigned)(lane * 16)) ^ swzn)) = ew.v;
    }
    __syncthreads();   // enc ready + booksT h0 staged

    // ---- matmul2: zqT[d][n] += booksT · encT, wave takes kstep = wave ----
#pragma unroll 1
    for (int h = 0; h < 2; ++h) {
      const int sb2 = wave * 64;            // (wave*32 s) * 2 bytes
      const unsigned swzn = (unsigned)(l15 & 7) << 4;
      short8 bf = *(const short8*)(encb + l15 * 1024 +
                   (((unsigned)(h * 512 + sb2 + g4 * 16)) ^ swzn));
#pragma unroll
      for (int m = 0; m < 4; ++m) {
        const int d = m * 16 + l15;
        short8 af = *(const short8*)(booksbuf + d * 512 +
                     (((unsigned)(sb2 + g4 * 16)) ^ (((unsigned)(d & 7)) << 4)));
        zacc[m] = __builtin_amdgcn_mfma_f32_16x16x32_bf16(af, bf, zacc[m], 0, 0, 0);
      }
      if (h == 0) {
        __syncthreads();                    // h0 reads done
        stage32k(booksbuf, bTimg + 32768, tid);
        __syncthreads();
      }
    }
  }

  // ---- zq cross-wave reduce + write ----
  __syncthreads();
#pragma unroll
  for (int m = 0; m < 4; ++m)
    *(f32x4*)(logitsb + wave * 4096 + l15 * 256 + m * 64 + g4 * 16) = zacc[m];
  __syncthreads();
  const int e = tid * 2;                    // 0..1022, covers 16*64 elems
  f32x2 acc = {0.f, 0.f};
#pragma unroll
  for (int w = 0; w < 8; ++w) acc += *(const f32x2*)(logitsb + w * 4096 + e * 4);
  *(f32x2*)(d_out + ((long)(b * 1024 + n0)) * 64 + e) = acc;
}

extern "C" void kernel_launch(void* const* d_in, const int* in_sizes, int n_in,
                              void* d_out, int out_size, void* d_ws, size_t ws_size,
                              hipStream_t stream) {
  (void)in_sizes; (void)n_in; (void)out_size; (void)ws_size;
  const float* ze     = (const float*)d_in[0];
  const float* cprobs = (const float*)d_in[1];
  const float* books  = (const float*)d_in[2];
  const float* lpq    = (const float*)d_in[3];
  const float* gum    = (const float*)d_in[4];
  float* out = (float*)d_out;
  char* ws = (char*)d_ws;
  hipLaunchKernelGGL(prep_ze_k,    dim3(32),  dim3(256), 0, stream, ze, ws);
  hipLaunchKernelGGL(prep_books_k, dim3(32),  dim3(256), 0, stream, books, lpq, ws, out);
  hipLaunchKernelGGL(gvq_main,     dim3(512), dim3(512), 0, stream, gum, cprobs, lpq, ws, out);
}